// Round 11
// baseline (254.219 us; speedup 1.0000x reference)
//
#include <hip/hip_runtime.h>
#include <math.h>

#define NDEV 50000
#define NTASK 100000
#define NE 1000000
#define NBK 98                 // coarse buckets per direction
#define SH_T 10                // task: dst>>10 -> 98 buckets of 1024 dsts
#define SH_D 9                 // dev:  dst>>9  -> 98 buckets of 512 dsts
#define NBLK_AB 512            // blocks per direction, passes A/B
#define CHUNK ((NE + NBLK_AB - 1) / NBLK_AB)   // 1954

typedef unsigned int uint;

__device__ inline uint bf16rn(float f) {
    uint x = __float_as_uint(f);
    return (x + 0x7fffu + ((x >> 16) & 1u)) >> 16;
}
__device__ inline uint bf16pair(float a, float b) {
    return bf16rn(a) | (bf16rn(b) << 16);
}
__device__ inline float blo(uint p) { return __uint_as_float(p << 16); }
__device__ inline float bhi(uint p) { return __uint_as_float(p & 0xffff0000u); }

// ---------------- weight prep: emit per-half concat matrices.
// layer1 halves [64][36]: [32 hs cols | 4 alpha folds]; layer2 halves [64][20]: [16 hs | 1 alpha | 3 pad]
__global__ void prep_weights(
    const float* __restrict__ W1a_src, const float* __restrict__ a1a_src,
    const float* __restrict__ W1a_dst, const float* __restrict__ a1a_dst,
    const float* __restrict__ W1b_src, const float* __restrict__ a1b_src,
    const float* __restrict__ W1b_dst, const float* __restrict__ a1b_dst,
    const float* __restrict__ W2a_src, const float* __restrict__ a2a_src,
    const float* __restrict__ W2a_dst, const float* __restrict__ a2a_dst,
    const float* __restrict__ W2b_src, const float* __restrict__ a2b_src,
    const float* __restrict__ W2b_dst, const float* __restrict__ a2b_dst,
    float* __restrict__ Whd1_0, float* __restrict__ Whd1_1,
    float* __restrict__ Wht1_0, float* __restrict__ Wht1_1,
    float* __restrict__ Whd2_0, float* __restrict__ Whd2_1,
    float* __restrict__ Wht2_0, float* __restrict__ Wht2_1)
{
    int f = threadIdx.x;
    if (f >= 64) return;
    for (int c = 0; c < 32; ++c) Whd1_0[f*36 + c] = W1a_src[f*64 + c];
    for (int h = 0; h < 4; ++h) {
        float s = 0.f;
        for (int c = 0; c < 16; ++c) s += W1a_src[f*64 + h*16 + c] * a1a_src[h*16 + c];
        Whd1_0[f*36 + 32 + h] = s;
    }
    for (int c = 0; c < 32; ++c) Whd1_1[f*36 + c] = W1a_src[f*64 + 32 + c];
    for (int h = 0; h < 4; ++h) {
        float s = 0.f;
        for (int c = 0; c < 16; ++c) s += W1b_dst[f*64 + h*16 + c] * a1b_dst[h*16 + c];
        Whd1_1[f*36 + 32 + h] = s;
    }
    for (int c = 0; c < 32; ++c) Wht1_0[f*36 + c] = W1b_src[f*64 + c];
    for (int h = 0; h < 4; ++h) {
        float s = 0.f;
        for (int c = 0; c < 16; ++c) s += W1b_src[f*64 + h*16 + c] * a1b_src[h*16 + c];
        Wht1_0[f*36 + 32 + h] = s;
    }
    for (int c = 0; c < 32; ++c) Wht1_1[f*36 + c] = W1b_src[f*64 + 32 + c];
    for (int h = 0; h < 4; ++h) {
        float s = 0.f;
        for (int c = 0; c < 16; ++c) s += W1a_dst[f*64 + h*16 + c] * a1a_dst[h*16 + c];
        Wht1_1[f*36 + 32 + h] = s;
    }
    for (int c = 0; c < 16; ++c) Whd2_0[f*20 + c] = W2a_src[f*32 + c];
    { float s = 0.f; for (int c = 0; c < 32; ++c) s += W2a_src[f*32+c]*a2a_src[c]; Whd2_0[f*20+16] = s; }
    Whd2_0[f*20+17] = 0.f; Whd2_0[f*20+18] = 0.f; Whd2_0[f*20+19] = 0.f;
    for (int c = 0; c < 16; ++c) Whd2_1[f*20 + c] = W2a_src[f*32 + 16 + c];
    { float s = 0.f; for (int c = 0; c < 32; ++c) s += W2b_dst[f*32+c]*a2b_dst[c]; Whd2_1[f*20+16] = s; }
    Whd2_1[f*20+17] = 0.f; Whd2_1[f*20+18] = 0.f; Whd2_1[f*20+19] = 0.f;
    for (int c = 0; c < 16; ++c) Wht2_0[f*20 + c] = W2b_src[f*32 + c];
    { float s = 0.f; for (int c = 0; c < 32; ++c) s += W2b_src[f*32+c]*a2b_src[c]; Wht2_0[f*20+16] = s; }
    Wht2_0[f*20+17] = 0.f; Wht2_0[f*20+18] = 0.f; Wht2_0[f*20+19] = 0.f;
    for (int c = 0; c < 16; ++c) Wht2_1[f*20 + c] = W2b_src[f*32 + 16 + c];
    { float s = 0.f; for (int c = 0; c < 32; ++c) s += W2a_dst[f*32+c]*a2a_dst[c]; Wht2_1[f*20+16] = s; }
    Wht2_1[f*20+17] = 0.f; Wht2_1[f*20+18] = 0.f; Wht2_1[f*20+19] = 0.f;
}

// ---------------- half-gemm body (fp32 input): X[N,64] @ Wc[64,COP]
template<int COP, int CHS, int NA, int AST, int HSTR>
__device__ __forceinline__ void gemm_half_block(
    const float* __restrict__ X, int N, const float* __restrict__ Wc,
    uint* __restrict__ hs, float* __restrict__ aout,
    int n0, int hsoff, float* w)
{
    for (int i = threadIdx.x; i < 64 * COP; i += 256) w[i] = Wc[i];
    __syncthreads();
    int n = n0 + threadIdx.x;
    if (n >= N) return;

    const float4* X4 = reinterpret_cast<const float4*>(X + (size_t)n * 64);
    float4 acc[CHS/4];
    #pragma unroll
    for (int j = 0; j < CHS/4; ++j) acc[j] = make_float4(0.f, 0.f, 0.f, 0.f);
    float aacc[NA];
    #pragma unroll
    for (int j = 0; j < NA; ++j) aacc[j] = 0.f;

    for (int k16 = 0; k16 < 4; ++k16) {
        float4 xv4[4];
        #pragma unroll
        for (int q = 0; q < 4; ++q) xv4[q] = X4[k16*4 + q];
        float xs[16];
        #pragma unroll
        for (int q = 0; q < 4; ++q) {
            xs[4*q+0] = xv4[q].x; xs[4*q+1] = xv4[q].y;
            xs[4*q+2] = xv4[q].z; xs[4*q+3] = xv4[q].w;
        }
        #pragma unroll
        for (int kk = 0; kk < 16; ++kk) {
            int k = k16*16 + kk;
            float xv = xs[kk];
            const float* wr = &w[k * COP];
            #pragma unroll
            for (int j = 0; j < CHS/4; ++j) {
                float4 wv = *reinterpret_cast<const float4*>(wr + 4*j);
                acc[j].x += xv * wv.x; acc[j].y += xv * wv.y;
                acc[j].z += xv * wv.z; acc[j].w += xv * wv.w;
            }
            #pragma unroll
            for (int j = 0; j < NA; ++j) aacc[j] += xv * wr[CHS + j];
        }
    }
    uint pk[CHS/2];
    #pragma unroll
    for (int j = 0; j < CHS/4; ++j) {
        pk[2*j]   = bf16pair(acc[j].x, acc[j].y);
        pk[2*j+1] = bf16pair(acc[j].z, acc[j].w);
    }
    uint4* hrow = reinterpret_cast<uint4*>(hs + (size_t)n * HSTR + hsoff);
    #pragma unroll
    for (int j = 0; j < CHS/8; ++j)
        hrow[j] = make_uint4(pk[4*j], pk[4*j+1], pk[4*j+2], pk[4*j+3]);
    #pragma unroll
    for (int j = 0; j < NA; ++j) aout[(size_t)n*AST + j] = aacc[j];
}

// ---------------- half-gemm body (packed-bf16 input, row = 32 dwords)
template<int COP, int CHS, int NA, int AST, int HSTR>
__device__ __forceinline__ void gemm_half_block_b16(
    const uint* __restrict__ X, int N, const float* __restrict__ Wc,
    uint* __restrict__ hs, float* __restrict__ aout,
    int n0, int hsoff, float* w)
{
    for (int i = threadIdx.x; i < 64 * COP; i += 256) w[i] = Wc[i];
    __syncthreads();
    int n = n0 + threadIdx.x;
    if (n >= N) return;

    const uint4* X4 = reinterpret_cast<const uint4*>(X + (size_t)n * 32);
    float4 acc[CHS/4];
    #pragma unroll
    for (int j = 0; j < CHS/4; ++j) acc[j] = make_float4(0.f, 0.f, 0.f, 0.f);
    float aacc[NA];
    #pragma unroll
    for (int j = 0; j < NA; ++j) aacc[j] = 0.f;

    for (int k16 = 0; k16 < 4; ++k16) {
        uint4 u0 = X4[2*k16], u1 = X4[2*k16 + 1];
        float xs[16];
        xs[0] = blo(u0.x); xs[1] = bhi(u0.x); xs[2] = blo(u0.y); xs[3] = bhi(u0.y);
        xs[4] = blo(u0.z); xs[5] = bhi(u0.z); xs[6] = blo(u0.w); xs[7] = bhi(u0.w);
        xs[8] = blo(u1.x); xs[9] = bhi(u1.x); xs[10] = blo(u1.y); xs[11] = bhi(u1.y);
        xs[12] = blo(u1.z); xs[13] = bhi(u1.z); xs[14] = blo(u1.w); xs[15] = bhi(u1.w);
        #pragma unroll
        for (int kk = 0; kk < 16; ++kk) {
            int k = k16*16 + kk;
            float xv = xs[kk];
            const float* wr = &w[k * COP];
            #pragma unroll
            for (int j = 0; j < CHS/4; ++j) {
                float4 wv = *reinterpret_cast<const float4*>(wr + 4*j);
                acc[j].x += xv * wv.x; acc[j].y += xv * wv.y;
                acc[j].z += xv * wv.z; acc[j].w += xv * wv.w;
            }
            #pragma unroll
            for (int j = 0; j < NA; ++j) aacc[j] += xv * wr[CHS + j];
        }
    }
    uint pk[CHS/2];
    #pragma unroll
    for (int j = 0; j < CHS/4; ++j) {
        pk[2*j]   = bf16pair(acc[j].x, acc[j].y);
        pk[2*j+1] = bf16pair(acc[j].z, acc[j].w);
    }
    uint4* hrow = reinterpret_cast<uint4*>(hs + (size_t)n * HSTR + hsoff);
    #pragma unroll
    for (int j = 0; j < CHS/8; ++j)
        hrow[j] = make_uint4(pk[4*j], pk[4*j+1], pk[4*j+2], pk[4*j+3]);
    #pragma unroll
    for (int j = 0; j < NA; ++j) aout[(size_t)n*AST + j] = aacc[j];
}

// quad launch: {half0, half1} x {nodetypeA, nodetypeB} in one grid (fp32 input)
template<int COP, int CHS, int NA, int AST, int HSTR>
__global__ __launch_bounds__(256, 4) void gemm_quad(
    const float* __restrict__ XA, int NrA,
    const float* __restrict__ WcA0, const float* __restrict__ WcA1,
    uint* __restrict__ hsA, float* __restrict__ alsA, float* __restrict__ aldA,
    const float* __restrict__ XB, int NrB,
    const float* __restrict__ WcB0, const float* __restrict__ WcB1,
    uint* __restrict__ hsB, float* __restrict__ alsB, float* __restrict__ aldB)
{
    __shared__ __align__(16) float w[64 * COP];
    int nbA = (NrA + 255) / 256;
    int nbB = (NrB + 255) / 256;
    int nbHalf = nbA + nbB;
    int b = (int)blockIdx.x;
    int half = b >= nbHalf ? 1 : 0;
    if (half) b -= nbHalf;
    int isB = b >= nbA ? 1 : 0;
    if (isB) b -= nbA;
    const float* X = isB ? XB : XA;
    int N = isB ? NrB : NrA;
    const float* Wc = isB ? (half ? WcB1 : WcB0) : (half ? WcA1 : WcA0);
    uint* hs = isB ? hsB : hsA;
    float* aout = isB ? (half ? aldB : alsB) : (half ? aldA : alsA);
    gemm_half_block<COP, CHS, NA, AST, HSTR>(X, N, Wc, hs, aout, b * 256, half * (CHS/2), w);
}

// quad launch, packed-bf16 input
template<int COP, int CHS, int NA, int AST, int HSTR>
__global__ __launch_bounds__(256, 4) void gemm_quad_b16(
    const uint* __restrict__ XA, int NrA,
    const float* __restrict__ WcA0, const float* __restrict__ WcA1,
    uint* __restrict__ hsA, float* __restrict__ alsA, float* __restrict__ aldA,
    const uint* __restrict__ XB, int NrB,
    const float* __restrict__ WcB0, const float* __restrict__ WcB1,
    uint* __restrict__ hsB, float* __restrict__ alsB, float* __restrict__ aldB)
{
    __shared__ __align__(16) float w[64 * COP];
    int nbA = (NrA + 255) / 256;
    int nbB = (NrB + 255) / 256;
    int nbHalf = nbA + nbB;
    int b = (int)blockIdx.x;
    int half = b >= nbHalf ? 1 : 0;
    if (half) b -= nbHalf;
    int isB = b >= nbA ? 1 : 0;
    if (isB) b -= nbA;
    const uint* X = isB ? XB : XA;
    int N = isB ? NrB : NrA;
    const float* Wc = isB ? (half ? WcB1 : WcB0) : (half ? WcA1 : WcA0);
    uint* hs = isB ? hsB : hsA;
    float* aout = isB ? (half ? aldB : alsB) : (half ? aldA : alsA);
    gemm_half_block_b16<COP, CHS, NA, AST, HSTR>(X, N, Wc, hs, aout, b * 256, half * (CHS/2), w);
}

// ---------------- CSR build via 2-level LDS bucket sort (unchanged)
__global__ __launch_bounds__(256) void bucketA(
    const int* __restrict__ wdst, const int* __restrict__ bdst,
    int* __restrict__ bh_t, int* __restrict__ bh_d)
{
    __shared__ int lh[128];
    int dir = (int)blockIdx.x >= NBLK_AB;
    int blk = (int)blockIdx.x - (dir ? NBLK_AB : 0);
    const int* dst = dir ? bdst : wdst;
    int sh = dir ? SH_D : SH_T;
    int* bh = dir ? bh_d : bh_t;
    for (int i = threadIdx.x; i < 128; i += 256) lh[i] = 0;
    __syncthreads();
    int e0 = blk * CHUNK, e1 = min(NE, e0 + CHUNK);
    for (int i = e0 + threadIdx.x; i < e1; i += 256)
        atomicAdd(&lh[dst[i] >> sh], 1);
    __syncthreads();
    if (threadIdx.x < NBK) bh[threadIdx.x * NBLK_AB + blk] = lh[threadIdx.x];
}

__global__ __launch_bounds__(256) void scanB1(
    int* __restrict__ bh_t, int* __restrict__ bh_d, int* __restrict__ rowtot)
{
    __shared__ int sm[256];
    int b = blockIdx.x;
    int dir = b >= NBK;
    int row = dir ? b - NBK : b;
    int* bh = dir ? bh_d : bh_t;
    int t = threadIdx.x;
    int base = row * NBLK_AB;
    int v0 = bh[base + 2*t], v1 = bh[base + 2*t + 1];
    int s = v0 + v1;
    sm[t] = s; __syncthreads();
    int x = s;
    for (int off = 1; off < 256; off <<= 1) {
        int y = (t >= off) ? sm[t - off] : 0;
        __syncthreads();
        x += y; sm[t] = x;
        __syncthreads();
    }
    int run = x - s;
    bh[base + 2*t] = run;
    bh[base + 2*t + 1] = run + v0;
    if (t == 255) rowtot[b] = x;
}

__global__ void scanB2(const int* __restrict__ rowtot,
                       int* __restrict__ coarse_t, int* __restrict__ coarse_d,
                       int* __restrict__ offs_task, int* __restrict__ offs_dev)
{
    __shared__ int sm[256];
    int t = threadIdx.x;
    int v = (t < NBK) ? rowtot[t] : 0;
    sm[t] = v; __syncthreads();
    int x = v;
    for (int off = 1; off < 256; off <<= 1) {
        int y = (t >= off) ? sm[t - off] : 0;
        __syncthreads();
        x += y; sm[t] = x;
        __syncthreads();
    }
    if (t < NBK) coarse_t[t] = x - v;
    __syncthreads();
    int v2 = (t < NBK) ? rowtot[NBK + t] : 0;
    sm[t] = v2; __syncthreads();
    int x2 = v2;
    for (int off = 1; off < 256; off <<= 1) {
        int y = (t >= off) ? sm[t - off] : 0;
        __syncthreads();
        x2 += y; sm[t] = x2;
        __syncthreads();
    }
    if (t < NBK) coarse_d[t] = x2 - v2;
    if (t == 0) {
        coarse_t[NBK] = NE; coarse_d[NBK] = NE;
        offs_task[NTASK] = NE; offs_dev[NDEV] = NE;
    }
}

__global__ __launch_bounds__(256) void bucketB(
    const int* __restrict__ wsrc, const int* __restrict__ wdst,
    const int* __restrict__ bsrc, const int* __restrict__ bdst,
    const int* __restrict__ bh_t, const int* __restrict__ bh_d,
    const int* __restrict__ coarse_t, const int* __restrict__ coarse_d,
    uint* __restrict__ pairs_w, uint* __restrict__ pairs_b)
{
    __shared__ int cur[128];
    int dir = (int)blockIdx.x >= NBLK_AB;
    int blk = (int)blockIdx.x - (dir ? NBLK_AB : 0);
    const int* src = dir ? bsrc : wsrc;
    const int* dst = dir ? bdst : wdst;
    int sh = dir ? SH_D : SH_T;
    uint msk = (1u << sh) - 1u;
    const int* bh = dir ? bh_d : bh_t;
    const int* coarse = dir ? coarse_d : coarse_t;
    uint* pairs = dir ? pairs_b : pairs_w;
    if (threadIdx.x < NBK)
        cur[threadIdx.x] = bh[threadIdx.x * NBLK_AB + blk] + coarse[threadIdx.x];
    __syncthreads();
    int e0 = blk * CHUNK, e1 = min(NE, e0 + CHUNK);
    for (int i = e0 + threadIdx.x; i < e1; i += 256) {
        int d = dst[i];
        int pos = atomicAdd(&cur[d >> sh], 1);
        pairs[pos] = (uint)src[i] | (((uint)d & msk) << 20);
    }
}

__global__ __launch_bounds__(256) void bucketC(
    const uint* __restrict__ pairs_w, const int* __restrict__ coarse_t,
    int* __restrict__ offs_task, int* __restrict__ s_w,
    const uint* __restrict__ pairs_b, const int* __restrict__ coarse_d,
    int* __restrict__ offs_dev, int* __restrict__ s_b)
{
    __shared__ int loff[1024];
    __shared__ int sm[256];
    int dir = (int)blockIdx.x >= NBK;
    int bkt = (int)blockIdx.x - (dir ? NBK : 0);
    const uint* pairs = dir ? pairs_b : pairs_w;
    const int* coarse = dir ? coarse_d : coarse_t;
    int* offs = dir ? offs_dev : offs_task;
    int* sarr = dir ? s_b : s_w;
    int sh = dir ? SH_D : SH_T;
    int rng = 1 << sh;
    int d0 = bkt << sh;
    int N = dir ? NDEV : NTASK;
    int dcnt = min(rng, N - d0);
    int e0 = coarse[bkt], e1 = coarse[bkt + 1];
    int t = threadIdx.x;
    for (int i = t; i < rng; i += 256) loff[i] = 0;
    __syncthreads();
    for (int i = e0 + t; i < e1; i += 256)
        atomicAdd(&loff[pairs[i] >> 20], 1);
    __syncthreads();
    int per = rng >> 8;            // 2 (dev) or 4 (task)
    int v[4]; int s = 0;
    for (int k = 0; k < per; ++k) { v[k] = loff[t * per + k]; s += v[k]; }
    sm[t] = s;
    __syncthreads();
    int x = s;
    for (int off = 1; off < 256; off <<= 1) {
        int y = (t >= off) ? sm[t - off] : 0;
        __syncthreads();
        x += y; sm[t] = x;
        __syncthreads();
    }
    int run = e0 + x - s;
    for (int k = 0; k < per; ++k) {
        int dl = t * per + k;
        loff[dl] = run;
        if (dl < dcnt) offs[d0 + dl] = run;
        run += v[k];
    }
    __syncthreads();
    for (int i = e0 + t; i < e1; i += 256) {
        uint u = pairs[i];
        int pos = atomicAdd(&loff[u >> 20], 1);
        sarr[pos] = (int)(u & 0xFFFFFu);
    }
}

// ---------------- layer-1 aggregation: wave per dst, EIGHTH-wave per edge (8 lanes),
// uint4 (16B) hs loads, 2 chains, src-index PREFETCH pipeline.
// lanes: sub = lane>>3 (edge slot 0..7), cl = lane&7 (dwords 4cl..4cl+3 = channels
// 8cl..8cl+7), h = cl>>1. Output packed bf16.
__global__ __launch_bounds__(256) void gat_agg_l1(
    const int* __restrict__ offs_t, const int* __restrict__ srcs_t,
    const float* __restrict__ als_d_, const float* __restrict__ ald_t,
    const uint* __restrict__ hs_d_, const float* __restrict__ bias_a, uint* __restrict__ out_t,
    const int* __restrict__ offs_d, const int* __restrict__ srcs_d,
    const float* __restrict__ als_t, const float* __restrict__ ald_d,
    const uint* __restrict__ hs_t, const float* __restrict__ bias_b, uint* __restrict__ out_d)
{
    const int nbT = (NTASK + 3) / 4;
    int wave = threadIdx.x >> 6, lane = threadIdx.x & 63;
    const int* offs; const int* srcs; const float* als; const float* ald;
    const uint* hs; const float* bias; uint* out; int Nd, d;
    if ((int)blockIdx.x < nbT) {
        offs = offs_t; srcs = srcs_t; als = als_d_; ald = ald_t; hs = hs_d_;
        bias = bias_a; out = out_t; Nd = NTASK; d = blockIdx.x * 4 + wave;
    } else {
        offs = offs_d; srcs = srcs_d; als = als_t; ald = ald_d; hs = hs_t;
        bias = bias_b; out = out_d; Nd = NDEV; d = ((int)blockIdx.x - nbT) * 4 + wave;
    }
    if (d >= Nd) return;
    int sub = lane >> 3;
    int cl  = lane & 7;
    int h   = cl >> 1;
    float aldv = ald[d * 4 + h];
    int beg = __builtin_amdgcn_readfirstlane(offs[d]);
    int end = __builtin_amdgcn_readfirstlane(offs[d + 1]);
    float denA = 0.f, a0A = 0.f, a1A = 0.f, a2A = 0.f, a3A = 0.f,
          a4A = 0.f, a5A = 0.f, a6A = 0.f, a7A = 0.f;
    float denB = 0.f, a0B = 0.f, a1B = 0.f, a2B = 0.f, a3B = 0.f,
          a4B = 0.f, a5B = 0.f, a6B = 0.f, a7B = 0.f;
    int iA = beg + sub, iB = beg + sub + 8;
    int sA = srcs[iA < end ? iA : beg];
    int sB = srcs[iB < end ? iB : beg];
    for (; iA < end; ) {
        int iA2 = iA + 16, iB2 = iB + 16;
        int sA2 = srcs[iA2 < end ? iA2 : beg];   // prefetch next (overlaps payload)
        int sB2 = srcs[iB2 < end ? iB2 : beg];
        bool vB = iB < end;
        float eA = als[sA * 4 + h] + aldv; eA = fmaxf(eA, 0.2f * eA);
        float eB = als[sB * 4 + h] + aldv; eB = fmaxf(eB, 0.2f * eB);
        float wA = __expf(eA);
        float wB = vB ? __expf(eB) : 0.f;
        uint4 pA = *reinterpret_cast<const uint4*>(hs + sA * 32 + 4 * cl);
        uint4 pB = *reinterpret_cast<const uint4*>(hs + sB * 32 + 4 * cl);
        denA += wA;
        a0A += wA * blo(pA.x); a1A += wA * bhi(pA.x);
        a2A += wA * blo(pA.y); a3A += wA * bhi(pA.y);
        a4A += wA * blo(pA.z); a5A += wA * bhi(pA.z);
        a6A += wA * blo(pA.w); a7A += wA * bhi(pA.w);
        denB += wB;
        a0B += wB * blo(pB.x); a1B += wB * bhi(pB.x);
        a2B += wB * blo(pB.y); a3B += wB * bhi(pB.y);
        a4B += wB * blo(pB.z); a5B += wB * bhi(pB.z);
        a6B += wB * blo(pB.w); a7B += wB * bhi(pB.w);
        iA = iA2; iB = iB2; sA = sA2; sB = sB2;
    }
    float den = denA + denB;
    float a0 = a0A + a0B, a1 = a1A + a1B, a2 = a2A + a2B, a3 = a3A + a3B;
    float a4 = a4A + a4B, a5 = a5A + a5B, a6 = a6A + a6B, a7 = a7A + a7B;
    den += __shfl_xor(den, 8, 64); den += __shfl_xor(den, 16, 64); den += __shfl_xor(den, 32, 64);
    a0 += __shfl_xor(a0, 8, 64); a0 += __shfl_xor(a0, 16, 64); a0 += __shfl_xor(a0, 32, 64);
    a1 += __shfl_xor(a1, 8, 64); a1 += __shfl_xor(a1, 16, 64); a1 += __shfl_xor(a1, 32, 64);
    a2 += __shfl_xor(a2, 8, 64); a2 += __shfl_xor(a2, 16, 64); a2 += __shfl_xor(a2, 32, 64);
    a3 += __shfl_xor(a3, 8, 64); a3 += __shfl_xor(a3, 16, 64); a3 += __shfl_xor(a3, 32, 64);
    a4 += __shfl_xor(a4, 8, 64); a4 += __shfl_xor(a4, 16, 64); a4 += __shfl_xor(a4, 32, 64);
    a5 += __shfl_xor(a5, 8, 64); a5 += __shfl_xor(a5, 16, 64); a5 += __shfl_xor(a5, 32, 64);
    a6 += __shfl_xor(a6, 8, 64); a6 += __shfl_xor(a6, 16, 64); a6 += __shfl_xor(a6, 32, 64);
    a7 += __shfl_xor(a7, 8, 64); a7 += __shfl_xor(a7, 16, 64); a7 += __shfl_xor(a7, 32, 64);
    if (lane < 8) {
        float inv = 1.f / (den + 1e-16f);
        float o0 = fmaxf(a0 * inv + bias[8*cl + 0], 0.f);
        float o1 = fmaxf(a1 * inv + bias[8*cl + 1], 0.f);
        float o2 = fmaxf(a2 * inv + bias[8*cl + 2], 0.f);
        float o3 = fmaxf(a3 * inv + bias[8*cl + 3], 0.f);
        float o4 = fmaxf(a4 * inv + bias[8*cl + 4], 0.f);
        float o5 = fmaxf(a5 * inv + bias[8*cl + 5], 0.f);
        float o6 = fmaxf(a6 * inv + bias[8*cl + 6], 0.f);
        float o7 = fmaxf(a7 * inv + bias[8*cl + 7], 0.f);
        uint4 pk;
        pk.x = bf16pair(o0, o1);
        pk.y = bf16pair(o2, o3);
        pk.z = bf16pair(o4, o5);
        pk.w = bf16pair(o6, o7);
        *reinterpret_cast<uint4*>(&out[(size_t)d * 32 + 4*cl]) = pk;
    }
}

// ---------------- layer-2 aggregation: wave per dst, QUARTER...16th-wave per edge
// (4 lanes), uint4 hs loads, 2 chains (32 edges in flight), src prefetch.
// lanes: sub = lane>>2 (0..15), cl = lane&3 (dwords 4cl..4cl+3 = ch 8cl..8cl+7).
__global__ __launch_bounds__(256) void gat_agg_l2(
    const int* __restrict__ offs_t, const int* __restrict__ srcs_t,
    const float* __restrict__ als_d_, const float* __restrict__ ald_t,
    const uint* __restrict__ hs_d_, const float* __restrict__ bias_a, float* __restrict__ out_t,
    const int* __restrict__ offs_d, const int* __restrict__ srcs_d,
    const float* __restrict__ als_t, const float* __restrict__ ald_d,
    const uint* __restrict__ hs_t, const float* __restrict__ bias_b, float* __restrict__ out_d)
{
    const int nbT = (NTASK + 3) / 4;
    int wave = threadIdx.x >> 6, lane = threadIdx.x & 63;
    const int* offs; const int* srcs; const float* als; const float* ald;
    const uint* hs; const float* bias; float* out; int Nd, d;
    if ((int)blockIdx.x < nbT) {
        offs = offs_t; srcs = srcs_t; als = als_d_; ald = ald_t; hs = hs_d_;
        bias = bias_a; out = out_t; Nd = NTASK; d = blockIdx.x * 4 + wave;
    } else {
        offs = offs_d; srcs = srcs_d; als = als_t; ald = ald_d; hs = hs_t;
        bias = bias_b; out = out_d; Nd = NDEV; d = ((int)blockIdx.x - nbT) * 4 + wave;
    }
    if (d >= Nd) return;
    int sub = lane >> 2;
    int cl  = lane & 3;
    float aldv = ald[d];
    int beg = __builtin_amdgcn_readfirstlane(offs[d]);
    int end = __builtin_amdgcn_readfirstlane(offs[d + 1]);
    float denA = 0.f, a0A = 0.f, a1A = 0.f, a2A = 0.f, a3A = 0.f,
          a4A = 0.f, a5A = 0.f, a6A = 0.f, a7A = 0.f;
    float denB = 0.f, a0B = 0.f, a1B = 0.f, a2B = 0.f, a3B = 0.f,
          a4B = 0.f, a5B = 0.f, a6B = 0.f, a7B = 0.f;
    int iA = beg + sub, iB = beg + sub + 16;
    int sA = srcs[iA < end ? iA : beg];
    int sB = srcs[iB < end ? iB : beg];
    for (; iA < end; ) {
        int iA2 = iA + 32, iB2 = iB + 32;
        int sA2 = srcs[iA2 < end ? iA2 : beg];
        int sB2 = srcs[iB2 < end ? iB2 : beg];
        bool vB = iB < end;
        float eA = als[sA] + aldv; eA = fmaxf(eA, 0.2f * eA);
        float eB = als[sB] + aldv; eB = fmaxf(eB, 0.2f * eB);
        float wA = __expf(eA);
        float wB = vB ? __expf(eB) : 0.f;
        uint4 pA = *reinterpret_cast<const uint4*>(hs + sA * 16 + 4 * cl);
        uint4 pB = *reinterpret_cast<const uint4*>(hs + sB * 16 + 4 * cl);
        denA += wA;
        a0A += wA * blo(pA.x); a1A += wA * bhi(pA.x);
        a2A += wA * blo(pA.y); a3A += wA * bhi(pA.y);
        a4A += wA * blo(pA.z); a5A += wA * bhi(pA.z);
        a6A += wA * blo(pA.w); a7A += wA * bhi(pA.w);
        denB += wB;
        a0B += wB * blo(pB.x); a1B += wB * bhi(pB.x);
        a2B += wB * blo(pB.y); a3B += wB * bhi(pB.y);
        a4B += wB * blo(pB.z); a5B += wB * bhi(pB.z);
        a6B += wB * blo(pB.w); a7B += wB * bhi(pB.w);
        iA = iA2; iB = iB2; sA = sA2; sB = sB2;
    }
    float den = denA + denB;
    float a0 = a0A + a0B, a1 = a1A + a1B, a2 = a2A + a2B, a3 = a3A + a3B;
    float a4 = a4A + a4B, a5 = a5A + a5B, a6 = a6A + a6B, a7 = a7A + a7B;
    den += __shfl_xor(den, 4, 64); den += __shfl_xor(den, 8, 64);
    den += __shfl_xor(den, 16, 64); den += __shfl_xor(den, 32, 64);
    a0 += __shfl_xor(a0, 4, 64); a0 += __shfl_xor(a0, 8, 64);
    a0 += __shfl_xor(a0, 16, 64); a0 += __shfl_xor(a0, 32, 64);
    a1 += __shfl_xor(a1, 4, 64); a1 += __shfl_xor(a1, 8, 64);
    a1 += __shfl_xor(a1, 16, 64); a1 += __shfl_xor(a1, 32, 64);
    a2 += __shfl_xor(a2, 4, 64); a2 += __shfl_xor(a2, 8, 64);
    a2 += __shfl_xor(a2, 16, 64); a2 += __shfl_xor(a2, 32, 64);
    a3 += __shfl_xor(a3, 4, 64); a3 += __shfl_xor(a3, 8, 64);
    a3 += __shfl_xor(a3, 16, 64); a3 += __shfl_xor(a3, 32, 64);
    a4 += __shfl_xor(a4, 4, 64); a4 += __shfl_xor(a4, 8, 64);
    a4 += __shfl_xor(a4, 16, 64); a4 += __shfl_xor(a4, 32, 64);
    a5 += __shfl_xor(a5, 4, 64); a5 += __shfl_xor(a5, 8, 64);
    a5 += __shfl_xor(a5, 16, 64); a5 += __shfl_xor(a5, 32, 64);
    a6 += __shfl_xor(a6, 4, 64); a6 += __shfl_xor(a6, 8, 64);
    a6 += __shfl_xor(a6, 16, 64); a6 += __shfl_xor(a6, 32, 64);
    a7 += __shfl_xor(a7, 4, 64); a7 += __shfl_xor(a7, 8, 64);
    a7 += __shfl_xor(a7, 16, 64); a7 += __shfl_xor(a7, 32, 64);
    if (lane < 4) {
        float inv = 1.f / (den + 1e-16f);
        float4 o0, o1;
        o0.x = fmaxf(a0 * inv + bias[8*cl + 0], 0.f);
        o0.y = fmaxf(a1 * inv + bias[8*cl + 1], 0.f);
        o0.z = fmaxf(a2 * inv + bias[8*cl + 2], 0.f);
        o0.w = fmaxf(a3 * inv + bias[8*cl + 3], 0.f);
        o1.x = fmaxf(a4 * inv + bias[8*cl + 4], 0.f);
        o1.y = fmaxf(a5 * inv + bias[8*cl + 5], 0.f);
        o1.z = fmaxf(a6 * inv + bias[8*cl + 6], 0.f);
        o1.w = fmaxf(a7 * inv + bias[8*cl + 7], 0.f);
        *reinterpret_cast<float4*>(&out[(size_t)d * 32 + 8*cl]) = o0;
        *reinterpret_cast<float4*>(&out[(size_t)d * 32 + 8*cl + 4]) = o1;
    }
}

// ---------------- launch
extern "C" void kernel_launch(void* const* d_in, const int* in_sizes, int n_in,
                              void* d_out, int out_size, void* d_ws, size_t ws_size,
                              hipStream_t stream)
{
    const float* x_dev   = (const float*)d_in[0];
    const float* x_task  = (const float*)d_in[1];
    const int* writes_src = (const int*)d_in[2];
    const int* writes_dst = (const int*)d_in[3];
    const int* wb_src     = (const int*)d_in[4];
    const int* wb_dst     = (const int*)d_in[5];
    const float* W1a_src = (const float*)d_in[6],  *W1a_dst = (const float*)d_in[7];
    const float* a1a_src = (const float*)d_in[8],  *a1a_dst = (const float*)d_in[9];
    const float* b1a     = (const float*)d_in[10];
    const float* W1b_src = (const float*)d_in[11], *W1b_dst = (const float*)d_in[12];
    const float* a1b_src = (const float*)d_in[13], *a1b_dst = (const float*)d_in[14];
    const float* b1b     = (const float*)d_in[15];
    const float* W2a_src = (const float*)d_in[16], *W2a_dst = (const float*)d_in[17];
    const float* a2a_src = (const float*)d_in[18], *a2a_dst = (const float*)d_in[19];
    const float* b2a     = (const float*)d_in[20];
    const float* W2b_src = (const float*)d_in[21], *W2b_dst = (const float*)d_in[22];
    const float* a2b_src = (const float*)d_in[23], *a2b_dst = (const float*)d_in[24];
    const float* b2b     = (const float*)d_in[25];

    float* out_dev2  = (float*)d_out;
    float* out_task2 = (float*)d_out + (size_t)NDEV * 32;

    char* ws = (char*)d_ws;
    size_t off = 0;
    auto take = [&](size_t bytes) -> void* {
        off = (off + 255) & ~(size_t)255;
        void* p = ws + off; off += bytes; return p;
    };
    int* s_w       = (int*)take((size_t)NE * 4);
    int* s_b       = (int*)take((size_t)NE * 4);
    int* offs_task = (int*)take((size_t)(NTASK + 1) * 4);
    int* offs_dev  = (int*)take((size_t)(NDEV + 1) * 4);
    int* bh_t      = (int*)take((size_t)NBK * NBLK_AB * 4);
    int* bh_d      = (int*)take((size_t)NBK * NBLK_AB * 4);
    int* coarse_t  = (int*)take((size_t)(NBK + 1) * 4);
    int* coarse_d  = (int*)take((size_t)(NBK + 1) * 4);
    int* rowtot    = (int*)take(256 * 4);
    float* Whd1_0  = (float*)take(64 * 36 * 4);
    float* Whd1_1  = (float*)take(64 * 36 * 4);
    float* Wht1_0  = (float*)take(64 * 36 * 4);
    float* Wht1_1  = (float*)take(64 * 36 * 4);
    float* Whd2_0  = (float*)take(64 * 20 * 4);
    float* Whd2_1  = (float*)take(64 * 20 * 4);
    float* Wht2_0  = (float*)take(64 * 20 * 4);
    float* Wht2_1  = (float*)take(64 * 20 * 4);
    uint* hs_dev    = (uint*)take((size_t)NDEV * 32 * 4);
    float* als_dev  = (float*)take((size_t)NDEV * 4 * 4);
    float* aldx_dev = (float*)take((size_t)NDEV * 4 * 4);
    uint* hs_task   = (uint*)take((size_t)NTASK * 32 * 4);
    float* als_task = (float*)take((size_t)NTASK * 4 * 4);
    float* aldx_task= (float*)take((size_t)NTASK * 4 * 4);
    uint* x_task1   = (uint*)take((size_t)NTASK * 32 * 4);  // packed bf16, 64 ch
    uint* x_dev1    = (uint*)take((size_t)NDEV * 32 * 4);   // packed bf16, 64 ch
    // pairs (4MB each) alias x_task1 (12.8MB): written by bucketB, consumed by
    // bucketC, both strictly before gat_agg_l1 writes x_task1 (in-order stream).
    uint* pairs_w = (uint*)x_task1;
    uint* pairs_b = pairs_w + NE;
    (void)ws_size; (void)n_in; (void)in_sizes; (void)out_size;

    prep_weights<<<1, 64, 0, stream>>>(
        W1a_src, a1a_src, W1a_dst, a1a_dst, W1b_src, a1b_src, W1b_dst, a1b_dst,
        W2a_src, a2a_src, W2a_dst, a2a_dst, W2b_src, a2b_src, W2b_dst, a2b_dst,
        Whd1_0, Whd1_1, Wht1_0, Wht1_1, Whd2_0, Whd2_1, Wht2_0, Wht2_1);

    // CSR build: 2-level bucket sort (both directions in each launch)
    bucketA<<<2 * NBLK_AB, 256, 0, stream>>>(writes_dst, wb_dst, bh_t, bh_d);
    scanB1<<<2 * NBK, 256, 0, stream>>>(bh_t, bh_d, rowtot);
    scanB2<<<1, 256, 0, stream>>>(rowtot, coarse_t, coarse_d, offs_task, offs_dev);
    bucketB<<<2 * NBLK_AB, 256, 0, stream>>>(writes_src, writes_dst, wb_src, wb_dst,
                                             bh_t, bh_d, coarse_t, coarse_d, pairs_w, pairs_b);
    bucketC<<<2 * NBK, 256, 0, stream>>>(pairs_w, coarse_t, offs_task, s_w,
                                         pairs_b, coarse_d, offs_dev, s_b);

    // layer 1 transforms: 2 halves x 2 node types in one launch
    int nbHalf = (NDEV + 255) / 256 + (NTASK + 255) / 256;
    gemm_quad<36, 32, 4, 4, 32><<<2 * nbHalf, 256, 0, stream>>>(
        x_dev, NDEV, Whd1_0, Whd1_1, hs_dev, als_dev, aldx_dev,
        x_task, NTASK, Wht1_0, Wht1_1, hs_task, als_task, aldx_task);

    // layer 1 aggregation (both directions, one launch) -> packed bf16 x1
    int nbagg = (NTASK + 3) / 4 + (NDEV + 3) / 4;
    gat_agg_l1<<<nbagg, 256, 0, stream>>>(
        offs_task, s_w, als_dev, aldx_task, hs_dev, b1a, x_task1,
        offs_dev, s_b, als_task, aldx_dev, hs_task, b1b, x_dev1);

    // layer 2 transforms (packed-bf16 input)
    gemm_quad_b16<20, 16, 1, 1, 16><<<2 * nbHalf, 256, 0, stream>>>(
        x_dev1, NDEV, Whd2_0, Whd2_1, hs_dev, als_dev, aldx_dev,
        x_task1, NTASK, Wht2_0, Wht2_1, hs_task, als_task, aldx_task);

    // layer 2 aggregation -> final outputs
    gat_agg_l2<<<nbagg, 256, 0, stream>>>(
        offs_task, s_w, als_dev, aldx_task, hs_dev, b2a, out_task2,
        offs_dev, s_b, als_task, aldx_dev, hs_task, b2b, out_dev2);
}

// Round 12
// 240.115 us; speedup vs baseline: 1.0587x; 1.0587x over previous
//
#include <hip/hip_runtime.h>
#include <math.h>

#define NDEV 50000
#define NTASK 100000
#define NE 1000000
#define NBK 98                 // coarse buckets per direction
#define SH_T 10                // task: dst>>10 -> 98 buckets of 1024 dsts
#define SH_D 9                 // dev:  dst>>9  -> 98 buckets of 512 dsts
#define NBLK_AB 512            // blocks per direction, passes A/B
#define CHUNK ((NE + NBLK_AB - 1) / NBLK_AB)   // 1954

typedef unsigned int uint;

__device__ inline uint bf16rn(float f) {
    uint x = __float_as_uint(f);
    return (x + 0x7fffu + ((x >> 16) & 1u)) >> 16;
}
__device__ inline uint bf16pair(float a, float b) {
    return bf16rn(a) | (bf16rn(b) << 16);
}
__device__ inline float blo(uint p) { return __uint_as_float(p << 16); }
__device__ inline float bhi(uint p) { return __uint_as_float(p & 0xffff0000u); }

// ---------------- weight prep: emit per-half concat matrices.
// layer1 halves [64][36]: [32 hs cols | 4 alpha folds]; layer2 halves [64][20]: [16 hs | 1 alpha | 3 pad]
__global__ void prep_weights(
    const float* __restrict__ W1a_src, const float* __restrict__ a1a_src,
    const float* __restrict__ W1a_dst, const float* __restrict__ a1a_dst,
    const float* __restrict__ W1b_src, const float* __restrict__ a1b_src,
    const float* __restrict__ W1b_dst, const float* __restrict__ a1b_dst,
    const float* __restrict__ W2a_src, const float* __restrict__ a2a_src,
    const float* __restrict__ W2a_dst, const float* __restrict__ a2a_dst,
    const float* __restrict__ W2b_src, const float* __restrict__ a2b_src,
    const float* __restrict__ W2b_dst, const float* __restrict__ a2b_dst,
    float* __restrict__ Whd1_0, float* __restrict__ Whd1_1,
    float* __restrict__ Wht1_0, float* __restrict__ Wht1_1,
    float* __restrict__ Whd2_0, float* __restrict__ Whd2_1,
    float* __restrict__ Wht2_0, float* __restrict__ Wht2_1)
{
    int f = threadIdx.x;
    if (f >= 64) return;
    for (int c = 0; c < 32; ++c) Whd1_0[f*36 + c] = W1a_src[f*64 + c];
    for (int h = 0; h < 4; ++h) {
        float s = 0.f;
        for (int c = 0; c < 16; ++c) s += W1a_src[f*64 + h*16 + c] * a1a_src[h*16 + c];
        Whd1_0[f*36 + 32 + h] = s;
    }
    for (int c = 0; c < 32; ++c) Whd1_1[f*36 + c] = W1a_src[f*64 + 32 + c];
    for (int h = 0; h < 4; ++h) {
        float s = 0.f;
        for (int c = 0; c < 16; ++c) s += W1b_dst[f*64 + h*16 + c] * a1b_dst[h*16 + c];
        Whd1_1[f*36 + 32 + h] = s;
    }
    for (int c = 0; c < 32; ++c) Wht1_0[f*36 + c] = W1b_src[f*64 + c];
    for (int h = 0; h < 4; ++h) {
        float s = 0.f;
        for (int c = 0; c < 16; ++c) s += W1b_src[f*64 + h*16 + c] * a1b_src[h*16 + c];
        Wht1_0[f*36 + 32 + h] = s;
    }
    for (int c = 0; c < 32; ++c) Wht1_1[f*36 + c] = W1b_src[f*64 + 32 + c];
    for (int h = 0; h < 4; ++h) {
        float s = 0.f;
        for (int c = 0; c < 16; ++c) s += W1a_dst[f*64 + h*16 + c] * a1a_dst[h*16 + c];
        Wht1_1[f*36 + 32 + h] = s;
    }
    for (int c = 0; c < 16; ++c) Whd2_0[f*20 + c] = W2a_src[f*32 + c];
    { float s = 0.f; for (int c = 0; c < 32; ++c) s += W2a_src[f*32+c]*a2a_src[c]; Whd2_0[f*20+16] = s; }
    Whd2_0[f*20+17] = 0.f; Whd2_0[f*20+18] = 0.f; Whd2_0[f*20+19] = 0.f;
    for (int c = 0; c < 16; ++c) Whd2_1[f*20 + c] = W2a_src[f*32 + 16 + c];
    { float s = 0.f; for (int c = 0; c < 32; ++c) s += W2b_dst[f*32+c]*a2b_dst[c]; Whd2_1[f*20+16] = s; }
    Whd2_1[f*20+17] = 0.f; Whd2_1[f*20+18] = 0.f; Whd2_1[f*20+19] = 0.f;
    for (int c = 0; c < 16; ++c) Wht2_0[f*20 + c] = W2b_src[f*32 + c];
    { float s = 0.f; for (int c = 0; c < 32; ++c) s += W2b_src[f*32+c]*a2b_src[c]; Wht2_0[f*20+16] = s; }
    Wht2_0[f*20+17] = 0.f; Wht2_0[f*20+18] = 0.f; Wht2_0[f*20+19] = 0.f;
    for (int c = 0; c < 16; ++c) Wht2_1[f*20 + c] = W2b_src[f*32 + 16 + c];
    { float s = 0.f; for (int c = 0; c < 32; ++c) s += W2a_dst[f*32+c]*a2a_dst[c]; Wht2_1[f*20+16] = s; }
    Wht2_1[f*20+17] = 0.f; Wht2_1[f*20+18] = 0.f; Wht2_1[f*20+19] = 0.f;
}

// ---------------- half-gemm body (fp32 input): X[N,64] @ Wc[64,COP]
template<int COP, int CHS, int NA, int AST, int HSTR>
__device__ __forceinline__ void gemm_half_block(
    const float* __restrict__ X, int N, const float* __restrict__ Wc,
    uint* __restrict__ hs, float* __restrict__ aout,
    int n0, int hsoff, float* w)
{
    for (int i = threadIdx.x; i < 64 * COP; i += 256) w[i] = Wc[i];
    __syncthreads();
    int n = n0 + threadIdx.x;
    if (n >= N) return;

    const float4* X4 = reinterpret_cast<const float4*>(X + (size_t)n * 64);
    float4 acc[CHS/4];
    #pragma unroll
    for (int j = 0; j < CHS/4; ++j) acc[j] = make_float4(0.f, 0.f, 0.f, 0.f);
    float aacc[NA];
    #pragma unroll
    for (int j = 0; j < NA; ++j) aacc[j] = 0.f;

    for (int k16 = 0; k16 < 4; ++k16) {
        float4 xv4[4];
        #pragma unroll
        for (int q = 0; q < 4; ++q) xv4[q] = X4[k16*4 + q];
        float xs[16];
        #pragma unroll
        for (int q = 0; q < 4; ++q) {
            xs[4*q+0] = xv4[q].x; xs[4*q+1] = xv4[q].y;
            xs[4*q+2] = xv4[q].z; xs[4*q+3] = xv4[q].w;
        }
        #pragma unroll
        for (int kk = 0; kk < 16; ++kk) {
            int k = k16*16 + kk;
            float xv = xs[kk];
            const float* wr = &w[k * COP];
            #pragma unroll
            for (int j = 0; j < CHS/4; ++j) {
                float4 wv = *reinterpret_cast<const float4*>(wr + 4*j);
                acc[j].x += xv * wv.x; acc[j].y += xv * wv.y;
                acc[j].z += xv * wv.z; acc[j].w += xv * wv.w;
            }
            #pragma unroll
            for (int j = 0; j < NA; ++j) aacc[j] += xv * wr[CHS + j];
        }
    }
    uint pk[CHS/2];
    #pragma unroll
    for (int j = 0; j < CHS/4; ++j) {
        pk[2*j]   = bf16pair(acc[j].x, acc[j].y);
        pk[2*j+1] = bf16pair(acc[j].z, acc[j].w);
    }
    uint4* hrow = reinterpret_cast<uint4*>(hs + (size_t)n * HSTR + hsoff);
    #pragma unroll
    for (int j = 0; j < CHS/8; ++j)
        hrow[j] = make_uint4(pk[4*j], pk[4*j+1], pk[4*j+2], pk[4*j+3]);
    #pragma unroll
    for (int j = 0; j < NA; ++j) aout[(size_t)n*AST + j] = aacc[j];
}

// ---------------- half-gemm body (packed-bf16 input, row = 32 dwords)
template<int COP, int CHS, int NA, int AST, int HSTR>
__device__ __forceinline__ void gemm_half_block_b16(
    const uint* __restrict__ X, int N, const float* __restrict__ Wc,
    uint* __restrict__ hs, float* __restrict__ aout,
    int n0, int hsoff, float* w)
{
    for (int i = threadIdx.x; i < 64 * COP; i += 256) w[i] = Wc[i];
    __syncthreads();
    int n = n0 + threadIdx.x;
    if (n >= N) return;

    const uint4* X4 = reinterpret_cast<const uint4*>(X + (size_t)n * 32);
    float4 acc[CHS/4];
    #pragma unroll
    for (int j = 0; j < CHS/4; ++j) acc[j] = make_float4(0.f, 0.f, 0.f, 0.f);
    float aacc[NA];
    #pragma unroll
    for (int j = 0; j < NA; ++j) aacc[j] = 0.f;

    for (int k16 = 0; k16 < 4; ++k16) {
        uint4 u0 = X4[2*k16], u1 = X4[2*k16 + 1];
        float xs[16];
        xs[0] = blo(u0.x); xs[1] = bhi(u0.x); xs[2] = blo(u0.y); xs[3] = bhi(u0.y);
        xs[4] = blo(u0.z); xs[5] = bhi(u0.z); xs[6] = blo(u0.w); xs[7] = bhi(u0.w);
        xs[8] = blo(u1.x); xs[9] = bhi(u1.x); xs[10] = blo(u1.y); xs[11] = bhi(u1.y);
        xs[12] = blo(u1.z); xs[13] = bhi(u1.z); xs[14] = blo(u1.w); xs[15] = bhi(u1.w);
        #pragma unroll
        for (int kk = 0; kk < 16; ++kk) {
            int k = k16*16 + kk;
            float xv = xs[kk];
            const float* wr = &w[k * COP];
            #pragma unroll
            for (int j = 0; j < CHS/4; ++j) {
                float4 wv = *reinterpret_cast<const float4*>(wr + 4*j);
                acc[j].x += xv * wv.x; acc[j].y += xv * wv.y;
                acc[j].z += xv * wv.z; acc[j].w += xv * wv.w;
            }
            #pragma unroll
            for (int j = 0; j < NA; ++j) aacc[j] += xv * wr[CHS + j];
        }
    }
    uint pk[CHS/2];
    #pragma unroll
    for (int j = 0; j < CHS/4; ++j) {
        pk[2*j]   = bf16pair(acc[j].x, acc[j].y);
        pk[2*j+1] = bf16pair(acc[j].z, acc[j].w);
    }
    uint4* hrow = reinterpret_cast<uint4*>(hs + (size_t)n * HSTR + hsoff);
    #pragma unroll
    for (int j = 0; j < CHS/8; ++j)
        hrow[j] = make_uint4(pk[4*j], pk[4*j+1], pk[4*j+2], pk[4*j+3]);
    #pragma unroll
    for (int j = 0; j < NA; ++j) aout[(size_t)n*AST + j] = aacc[j];
}

// quad launch: {half0, half1} x {nodetypeA, nodetypeB} in one grid (fp32 input)
template<int COP, int CHS, int NA, int AST, int HSTR>
__global__ __launch_bounds__(256, 4) void gemm_quad(
    const float* __restrict__ XA, int NrA,
    const float* __restrict__ WcA0, const float* __restrict__ WcA1,
    uint* __restrict__ hsA, float* __restrict__ alsA, float* __restrict__ aldA,
    const float* __restrict__ XB, int NrB,
    const float* __restrict__ WcB0, const float* __restrict__ WcB1,
    uint* __restrict__ hsB, float* __restrict__ alsB, float* __restrict__ aldB)
{
    __shared__ __align__(16) float w[64 * COP];
    int nbA = (NrA + 255) / 256;
    int nbB = (NrB + 255) / 256;
    int nbHalf = nbA + nbB;
    int b = (int)blockIdx.x;
    int half = b >= nbHalf ? 1 : 0;
    if (half) b -= nbHalf;
    int isB = b >= nbA ? 1 : 0;
    if (isB) b -= nbA;
    const float* X = isB ? XB : XA;
    int N = isB ? NrB : NrA;
    const float* Wc = isB ? (half ? WcB1 : WcB0) : (half ? WcA1 : WcA0);
    uint* hs = isB ? hsB : hsA;
    float* aout = isB ? (half ? aldB : alsB) : (half ? aldA : alsA);
    gemm_half_block<COP, CHS, NA, AST, HSTR>(X, N, Wc, hs, aout, b * 256, half * (CHS/2), w);
}

// quad launch, packed-bf16 input
template<int COP, int CHS, int NA, int AST, int HSTR>
__global__ __launch_bounds__(256, 4) void gemm_quad_b16(
    const uint* __restrict__ XA, int NrA,
    const float* __restrict__ WcA0, const float* __restrict__ WcA1,
    uint* __restrict__ hsA, float* __restrict__ alsA, float* __restrict__ aldA,
    const uint* __restrict__ XB, int NrB,
    const float* __restrict__ WcB0, const float* __restrict__ WcB1,
    uint* __restrict__ hsB, float* __restrict__ alsB, float* __restrict__ aldB)
{
    __shared__ __align__(16) float w[64 * COP];
    int nbA = (NrA + 255) / 256;
    int nbB = (NrB + 255) / 256;
    int nbHalf = nbA + nbB;
    int b = (int)blockIdx.x;
    int half = b >= nbHalf ? 1 : 0;
    if (half) b -= nbHalf;
    int isB = b >= nbA ? 1 : 0;
    if (isB) b -= nbA;
    const uint* X = isB ? XB : XA;
    int N = isB ? NrB : NrA;
    const float* Wc = isB ? (half ? WcB1 : WcB0) : (half ? WcA1 : WcA0);
    uint* hs = isB ? hsB : hsA;
    float* aout = isB ? (half ? aldB : alsB) : (half ? aldA : alsA);
    gemm_half_block_b16<COP, CHS, NA, AST, HSTR>(X, N, Wc, hs, aout, b * 256, half * (CHS/2), w);
}

// ---------------- CSR build via 2-level LDS bucket sort (unchanged)
__global__ __launch_bounds__(256) void bucketA(
    const int* __restrict__ wdst, const int* __restrict__ bdst,
    int* __restrict__ bh_t, int* __restrict__ bh_d)
{
    __shared__ int lh[128];
    int dir = (int)blockIdx.x >= NBLK_AB;
    int blk = (int)blockIdx.x - (dir ? NBLK_AB : 0);
    const int* dst = dir ? bdst : wdst;
    int sh = dir ? SH_D : SH_T;
    int* bh = dir ? bh_d : bh_t;
    for (int i = threadIdx.x; i < 128; i += 256) lh[i] = 0;
    __syncthreads();
    int e0 = blk * CHUNK, e1 = min(NE, e0 + CHUNK);
    for (int i = e0 + threadIdx.x; i < e1; i += 256)
        atomicAdd(&lh[dst[i] >> sh], 1);
    __syncthreads();
    if (threadIdx.x < NBK) bh[threadIdx.x * NBLK_AB + blk] = lh[threadIdx.x];
}

__global__ __launch_bounds__(256) void scanB1(
    int* __restrict__ bh_t, int* __restrict__ bh_d, int* __restrict__ rowtot)
{
    __shared__ int sm[256];
    int b = blockIdx.x;
    int dir = b >= NBK;
    int row = dir ? b - NBK : b;
    int* bh = dir ? bh_d : bh_t;
    int t = threadIdx.x;
    int base = row * NBLK_AB;
    int v0 = bh[base + 2*t], v1 = bh[base + 2*t + 1];
    int s = v0 + v1;
    sm[t] = s; __syncthreads();
    int x = s;
    for (int off = 1; off < 256; off <<= 1) {
        int y = (t >= off) ? sm[t - off] : 0;
        __syncthreads();
        x += y; sm[t] = x;
        __syncthreads();
    }
    int run = x - s;
    bh[base + 2*t] = run;
    bh[base + 2*t + 1] = run + v0;
    if (t == 255) rowtot[b] = x;
}

__global__ void scanB2(const int* __restrict__ rowtot,
                       int* __restrict__ coarse_t, int* __restrict__ coarse_d,
                       int* __restrict__ offs_task, int* __restrict__ offs_dev)
{
    __shared__ int sm[256];
    int t = threadIdx.x;
    int v = (t < NBK) ? rowtot[t] : 0;
    sm[t] = v; __syncthreads();
    int x = v;
    for (int off = 1; off < 256; off <<= 1) {
        int y = (t >= off) ? sm[t - off] : 0;
        __syncthreads();
        x += y; sm[t] = x;
        __syncthreads();
    }
    if (t < NBK) coarse_t[t] = x - v;
    __syncthreads();
    int v2 = (t < NBK) ? rowtot[NBK + t] : 0;
    sm[t] = v2; __syncthreads();
    int x2 = v2;
    for (int off = 1; off < 256; off <<= 1) {
        int y = (t >= off) ? sm[t - off] : 0;
        __syncthreads();
        x2 += y; sm[t] = x2;
        __syncthreads();
    }
    if (t < NBK) coarse_d[t] = x2 - v2;
    if (t == 0) {
        coarse_t[NBK] = NE; coarse_d[NBK] = NE;
        offs_task[NTASK] = NE; offs_dev[NDEV] = NE;
    }
}

__global__ __launch_bounds__(256) void bucketB(
    const int* __restrict__ wsrc, const int* __restrict__ wdst,
    const int* __restrict__ bsrc, const int* __restrict__ bdst,
    const int* __restrict__ bh_t, const int* __restrict__ bh_d,
    const int* __restrict__ coarse_t, const int* __restrict__ coarse_d,
    uint* __restrict__ pairs_w, uint* __restrict__ pairs_b)
{
    __shared__ int cur[128];
    int dir = (int)blockIdx.x >= NBLK_AB;
    int blk = (int)blockIdx.x - (dir ? NBLK_AB : 0);
    const int* src = dir ? bsrc : wsrc;
    const int* dst = dir ? bdst : wdst;
    int sh = dir ? SH_D : SH_T;
    uint msk = (1u << sh) - 1u;
    const int* bh = dir ? bh_d : bh_t;
    const int* coarse = dir ? coarse_d : coarse_t;
    uint* pairs = dir ? pairs_b : pairs_w;
    if (threadIdx.x < NBK)
        cur[threadIdx.x] = bh[threadIdx.x * NBLK_AB + blk] + coarse[threadIdx.x];
    __syncthreads();
    int e0 = blk * CHUNK, e1 = min(NE, e0 + CHUNK);
    for (int i = e0 + threadIdx.x; i < e1; i += 256) {
        int d = dst[i];
        int pos = atomicAdd(&cur[d >> sh], 1);
        pairs[pos] = (uint)src[i] | (((uint)d & msk) << 20);
    }
}

__global__ __launch_bounds__(256) void bucketC(
    const uint* __restrict__ pairs_w, const int* __restrict__ coarse_t,
    int* __restrict__ offs_task, int* __restrict__ s_w,
    const uint* __restrict__ pairs_b, const int* __restrict__ coarse_d,
    int* __restrict__ offs_dev, int* __restrict__ s_b)
{
    __shared__ int loff[1024];
    __shared__ int sm[256];
    int dir = (int)blockIdx.x >= NBK;
    int bkt = (int)blockIdx.x - (dir ? NBK : 0);
    const uint* pairs = dir ? pairs_b : pairs_w;
    const int* coarse = dir ? coarse_d : coarse_t;
    int* offs = dir ? offs_dev : offs_task;
    int* sarr = dir ? s_b : s_w;
    int sh = dir ? SH_D : SH_T;
    int rng = 1 << sh;
    int d0 = bkt << sh;
    int N = dir ? NDEV : NTASK;
    int dcnt = min(rng, N - d0);
    int e0 = coarse[bkt], e1 = coarse[bkt + 1];
    int t = threadIdx.x;
    for (int i = t; i < rng; i += 256) loff[i] = 0;
    __syncthreads();
    for (int i = e0 + t; i < e1; i += 256)
        atomicAdd(&loff[pairs[i] >> 20], 1);
    __syncthreads();
    int per = rng >> 8;            // 2 (dev) or 4 (task)
    int v[4]; int s = 0;
    for (int k = 0; k < per; ++k) { v[k] = loff[t * per + k]; s += v[k]; }
    sm[t] = s;
    __syncthreads();
    int x = s;
    for (int off = 1; off < 256; off <<= 1) {
        int y = (t >= off) ? sm[t - off] : 0;
        __syncthreads();
        x += y; sm[t] = x;
        __syncthreads();
    }
    int run = e0 + x - s;
    for (int k = 0; k < per; ++k) {
        int dl = t * per + k;
        loff[dl] = run;
        if (dl < dcnt) offs[d0 + dl] = run;
        run += v[k];
    }
    __syncthreads();
    for (int i = e0 + t; i < e1; i += 256) {
        uint u = pairs[i];
        int pos = atomicAdd(&loff[u >> 20], 1);
        sarr[pos] = (int)(u & 0xFFFFFu);
    }
}

// ---------------- layer-1 aggregation (r11-proven): wave per dst, eighth-wave
// per edge (8 lanes), uint4 (16B) hs loads, 2 chains, src-index prefetch.
// Output packed bf16.
__global__ __launch_bounds__(256) void gat_agg_l1(
    const int* __restrict__ offs_t, const int* __restrict__ srcs_t,
    const float* __restrict__ als_d_, const float* __restrict__ ald_t,
    const uint* __restrict__ hs_d_, const float* __restrict__ bias_a, uint* __restrict__ out_t,
    const int* __restrict__ offs_d, const int* __restrict__ srcs_d,
    const float* __restrict__ als_t, const float* __restrict__ ald_d,
    const uint* __restrict__ hs_t, const float* __restrict__ bias_b, uint* __restrict__ out_d)
{
    const int nbT = (NTASK + 3) / 4;
    int wave = threadIdx.x >> 6, lane = threadIdx.x & 63;
    const int* offs; const int* srcs; const float* als; const float* ald;
    const uint* hs; const float* bias; uint* out; int Nd, d;
    if ((int)blockIdx.x < nbT) {
        offs = offs_t; srcs = srcs_t; als = als_d_; ald = ald_t; hs = hs_d_;
        bias = bias_a; out = out_t; Nd = NTASK; d = blockIdx.x * 4 + wave;
    } else {
        offs = offs_d; srcs = srcs_d; als = als_t; ald = ald_d; hs = hs_t;
        bias = bias_b; out = out_d; Nd = NDEV; d = ((int)blockIdx.x - nbT) * 4 + wave;
    }
    if (d >= Nd) return;
    int sub = lane >> 3;
    int cl  = lane & 7;
    int h   = cl >> 1;
    float aldv = ald[d * 4 + h];
    int beg = __builtin_amdgcn_readfirstlane(offs[d]);
    int end = __builtin_amdgcn_readfirstlane(offs[d + 1]);
    float denA = 0.f, a0A = 0.f, a1A = 0.f, a2A = 0.f, a3A = 0.f,
          a4A = 0.f, a5A = 0.f, a6A = 0.f, a7A = 0.f;
    float denB = 0.f, a0B = 0.f, a1B = 0.f, a2B = 0.f, a3B = 0.f,
          a4B = 0.f, a5B = 0.f, a6B = 0.f, a7B = 0.f;
    int iA = beg + sub, iB = beg + sub + 8;
    int sA = srcs[iA < end ? iA : beg];
    int sB = srcs[iB < end ? iB : beg];
    for (; iA < end; ) {
        int iA2 = iA + 16, iB2 = iB + 16;
        int sA2 = srcs[iA2 < end ? iA2 : beg];   // prefetch next (overlaps payload)
        int sB2 = srcs[iB2 < end ? iB2 : beg];
        bool vB = iB < end;
        float eA = als[sA * 4 + h] + aldv; eA = fmaxf(eA, 0.2f * eA);
        float eB = als[sB * 4 + h] + aldv; eB = fmaxf(eB, 0.2f * eB);
        float wA = __expf(eA);
        float wB = vB ? __expf(eB) : 0.f;
        uint4 pA = *reinterpret_cast<const uint4*>(hs + sA * 32 + 4 * cl);
        uint4 pB = *reinterpret_cast<const uint4*>(hs + sB * 32 + 4 * cl);
        denA += wA;
        a0A += wA * blo(pA.x); a1A += wA * bhi(pA.x);
        a2A += wA * blo(pA.y); a3A += wA * bhi(pA.y);
        a4A += wA * blo(pA.z); a5A += wA * bhi(pA.z);
        a6A += wA * blo(pA.w); a7A += wA * bhi(pA.w);
        denB += wB;
        a0B += wB * blo(pB.x); a1B += wB * bhi(pB.x);
        a2B += wB * blo(pB.y); a3B += wB * bhi(pB.y);
        a4B += wB * blo(pB.z); a5B += wB * bhi(pB.z);
        a6B += wB * blo(pB.w); a7B += wB * bhi(pB.w);
        iA = iA2; iB = iB2; sA = sA2; sB = sB2;
    }
    float den = denA + denB;
    float a0 = a0A + a0B, a1 = a1A + a1B, a2 = a2A + a2B, a3 = a3A + a3B;
    float a4 = a4A + a4B, a5 = a5A + a5B, a6 = a6A + a6B, a7 = a7A + a7B;
    den += __shfl_xor(den, 8, 64); den += __shfl_xor(den, 16, 64); den += __shfl_xor(den, 32, 64);
    a0 += __shfl_xor(a0, 8, 64); a0 += __shfl_xor(a0, 16, 64); a0 += __shfl_xor(a0, 32, 64);
    a1 += __shfl_xor(a1, 8, 64); a1 += __shfl_xor(a1, 16, 64); a1 += __shfl_xor(a1, 32, 64);
    a2 += __shfl_xor(a2, 8, 64); a2 += __shfl_xor(a2, 16, 64); a2 += __shfl_xor(a2, 32, 64);
    a3 += __shfl_xor(a3, 8, 64); a3 += __shfl_xor(a3, 16, 64); a3 += __shfl_xor(a3, 32, 64);
    a4 += __shfl_xor(a4, 8, 64); a4 += __shfl_xor(a4, 16, 64); a4 += __shfl_xor(a4, 32, 64);
    a5 += __shfl_xor(a5, 8, 64); a5 += __shfl_xor(a5, 16, 64); a5 += __shfl_xor(a5, 32, 64);
    a6 += __shfl_xor(a6, 8, 64); a6 += __shfl_xor(a6, 16, 64); a6 += __shfl_xor(a6, 32, 64);
    a7 += __shfl_xor(a7, 8, 64); a7 += __shfl_xor(a7, 16, 64); a7 += __shfl_xor(a7, 32, 64);
    if (lane < 8) {
        float inv = 1.f / (den + 1e-16f);
        float o0 = fmaxf(a0 * inv + bias[8*cl + 0], 0.f);
        float o1 = fmaxf(a1 * inv + bias[8*cl + 1], 0.f);
        float o2 = fmaxf(a2 * inv + bias[8*cl + 2], 0.f);
        float o3 = fmaxf(a3 * inv + bias[8*cl + 3], 0.f);
        float o4 = fmaxf(a4 * inv + bias[8*cl + 4], 0.f);
        float o5 = fmaxf(a5 * inv + bias[8*cl + 5], 0.f);
        float o6 = fmaxf(a6 * inv + bias[8*cl + 6], 0.f);
        float o7 = fmaxf(a7 * inv + bias[8*cl + 7], 0.f);
        uint4 pk;
        pk.x = bf16pair(o0, o1);
        pk.y = bf16pair(o2, o3);
        pk.z = bf16pair(o4, o5);
        pk.w = bf16pair(o6, o7);
        *reinterpret_cast<uint4*>(&out[(size_t)d * 32 + 4*cl]) = pk;
    }
}

// ---------------- layer-2 aggregation (r10-proven): wave per dst, eighth-wave
// per edge, uint2 hs loads, FOUR independent edge-chains (32 edges in flight).
__global__ __launch_bounds__(256) void gat_agg_l2(
    const int* __restrict__ offs_t, const int* __restrict__ srcs_t,
    const float* __restrict__ als_d_, const float* __restrict__ ald_t,
    const uint* __restrict__ hs_d_, const float* __restrict__ bias_a, float* __restrict__ out_t,
    const int* __restrict__ offs_d, const int* __restrict__ srcs_d,
    const float* __restrict__ als_t, const float* __restrict__ ald_d,
    const uint* __restrict__ hs_t, const float* __restrict__ bias_b, float* __restrict__ out_d)
{
    const int nbT = (NTASK + 3) / 4;
    int wave = threadIdx.x >> 6, lane = threadIdx.x & 63;
    const int* offs; const int* srcs; const float* als; const float* ald;
    const uint* hs; const float* bias; float* out; int Nd, d;
    if ((int)blockIdx.x < nbT) {
        offs = offs_t; srcs = srcs_t; als = als_d_; ald = ald_t; hs = hs_d_;
        bias = bias_a; out = out_t; Nd = NTASK; d = blockIdx.x * 4 + wave;
    } else {
        offs = offs_d; srcs = srcs_d; als = als_t; ald = ald_d; hs = hs_t;
        bias = bias_b; out = out_d; Nd = NDEV; d = ((int)blockIdx.x - nbT) * 4 + wave;
    }
    if (d >= Nd) return;
    int sub = lane >> 3;
    int cl  = lane & 7;
    float aldv = ald[d];
    int beg = __builtin_amdgcn_readfirstlane(offs[d]);
    int end = __builtin_amdgcn_readfirstlane(offs[d + 1]);
    float denA = 0.f, a0A = 0.f, a1A = 0.f, a2A = 0.f, a3A = 0.f;
    float denB = 0.f, a0B = 0.f, a1B = 0.f, a2B = 0.f, a3B = 0.f;
    float denC = 0.f, a0C = 0.f, a1C = 0.f, a2C = 0.f, a3C = 0.f;
    float denD = 0.f, a0D = 0.f, a1D = 0.f, a2D = 0.f, a3D = 0.f;
    for (int i0 = beg + sub; i0 < end; i0 += 32) {
        int iB = i0 + 8, iC = i0 + 16, iD = i0 + 24;
        bool vB = iB < end, vC = iC < end, vD = iD < end;
        int sA = srcs[i0];
        int sB = srcs[vB ? iB : beg];
        int sC = srcs[vC ? iC : beg];
        int sD = srcs[vD ? iD : beg];
        float eA = als[sA] + aldv; eA = fmaxf(eA, 0.2f * eA);
        float eB = als[sB] + aldv; eB = fmaxf(eB, 0.2f * eB);
        float eC = als[sC] + aldv; eC = fmaxf(eC, 0.2f * eC);
        float eD = als[sD] + aldv; eD = fmaxf(eD, 0.2f * eD);
        float wA = __expf(eA);
        float wB = vB ? __expf(eB) : 0.f;
        float wC = vC ? __expf(eC) : 0.f;
        float wD = vD ? __expf(eD) : 0.f;
        uint2 pA = *reinterpret_cast<const uint2*>(hs + sA * 16 + 2 * cl);
        uint2 pB = *reinterpret_cast<const uint2*>(hs + sB * 16 + 2 * cl);
        uint2 pC = *reinterpret_cast<const uint2*>(hs + sC * 16 + 2 * cl);
        uint2 pD = *reinterpret_cast<const uint2*>(hs + sD * 16 + 2 * cl);
        denA += wA;
        a0A += wA * blo(pA.x); a1A += wA * bhi(pA.x);
        a2A += wA * blo(pA.y); a3A += wA * bhi(pA.y);
        denB += wB;
        a0B += wB * blo(pB.x); a1B += wB * bhi(pB.x);
        a2B += wB * blo(pB.y); a3B += wB * bhi(pB.y);
        denC += wC;
        a0C += wC * blo(pC.x); a1C += wC * bhi(pC.x);
        a2C += wC * blo(pC.y); a3C += wC * bhi(pC.y);
        denD += wD;
        a0D += wD * blo(pD.x); a1D += wD * bhi(pD.x);
        a2D += wD * blo(pD.y); a3D += wD * bhi(pD.y);
    }
    float den = (denA + denB) + (denC + denD);
    float a0 = (a0A + a0B) + (a0C + a0D);
    float a1 = (a1A + a1B) + (a1C + a1D);
    float a2 = (a2A + a2B) + (a2C + a2D);
    float a3 = (a3A + a3B) + (a3C + a3D);
    den += __shfl_xor(den, 8, 64); den += __shfl_xor(den, 16, 64); den += __shfl_xor(den, 32, 64);
    a0  += __shfl_xor(a0, 8, 64);  a0  += __shfl_xor(a0, 16, 64);  a0  += __shfl_xor(a0, 32, 64);
    a1  += __shfl_xor(a1, 8, 64);  a1  += __shfl_xor(a1, 16, 64);  a1  += __shfl_xor(a1, 32, 64);
    a2  += __shfl_xor(a2, 8, 64);  a2  += __shfl_xor(a2, 16, 64);  a2  += __shfl_xor(a2, 32, 64);
    a3  += __shfl_xor(a3, 8, 64);  a3  += __shfl_xor(a3, 16, 64);  a3  += __shfl_xor(a3, 32, 64);
    if (lane < 8) {
        float inv = 1.f / (den + 1e-16f);
        float4 o;
        o.x = fmaxf(a0 * inv + bias[4*cl + 0], 0.f);
        o.y = fmaxf(a1 * inv + bias[4*cl + 1], 0.f);
        o.z = fmaxf(a2 * inv + bias[4*cl + 2], 0.f);
        o.w = fmaxf(a3 * inv + bias[4*cl + 3], 0.f);
        *reinterpret_cast<float4*>(&out[(size_t)d * 32 + 4*cl]) = o;
    }
}

// ---------------- launch
extern "C" void kernel_launch(void* const* d_in, const int* in_sizes, int n_in,
                              void* d_out, int out_size, void* d_ws, size_t ws_size,
                              hipStream_t stream)
{
    const float* x_dev   = (const float*)d_in[0];
    const float* x_task  = (const float*)d_in[1];
    const int* writes_src = (const int*)d_in[2];
    const int* writes_dst = (const int*)d_in[3];
    const int* wb_src     = (const int*)d_in[4];
    const int* wb_dst     = (const int*)d_in[5];
    const float* W1a_src = (const float*)d_in[6],  *W1a_dst = (const float*)d_in[7];
    const float* a1a_src = (const float*)d_in[8],  *a1a_dst = (const float*)d_in[9];
    const float* b1a     = (const float*)d_in[10];
    const float* W1b_src = (const float*)d_in[11], *W1b_dst = (const float*)d_in[12];
    const float* a1b_src = (const float*)d_in[13], *a1b_dst = (const float*)d_in[14];
    const float* b1b     = (const float*)d_in[15];
    const float* W2a_src = (const float*)d_in[16], *W2a_dst = (const float*)d_in[17];
    const float* a2a_src = (const float*)d_in[18], *a2a_dst = (const float*)d_in[19];
    const float* b2a     = (const float*)d_in[20];
    const float* W2b_src = (const float*)d_in[21], *W2b_dst = (const float*)d_in[22];
    const float* a2b_src = (const float*)d_in[23], *a2b_dst = (const float*)d_in[24];
    const float* b2b     = (const float*)d_in[25];

    float* out_dev2  = (float*)d_out;
    float* out_task2 = (float*)d_out + (size_t)NDEV * 32;

    char* ws = (char*)d_ws;
    size_t off = 0;
    auto take = [&](size_t bytes) -> void* {
        off = (off + 255) & ~(size_t)255;
        void* p = ws + off; off += bytes; return p;
    };
    int* s_w       = (int*)take((size_t)NE * 4);
    int* s_b       = (int*)take((size_t)NE * 4);
    int* offs_task = (int*)take((size_t)(NTASK + 1) * 4);
    int* offs_dev  = (int*)take((size_t)(NDEV + 1) * 4);
    int* bh_t      = (int*)take((size_t)NBK * NBLK_AB * 4);
    int* bh_d      = (int*)take((size_t)NBK * NBLK_AB * 4);
    int* coarse_t  = (int*)take((size_t)(NBK + 1) * 4);
    int* coarse_d  = (int*)take((size_t)(NBK + 1) * 4);
    int* rowtot    = (int*)take(256 * 4);
    float* Whd1_0  = (float*)take(64 * 36 * 4);
    float* Whd1_1  = (float*)take(64 * 36 * 4);
    float* Wht1_0  = (float*)take(64 * 36 * 4);
    float* Wht1_1  = (float*)take(64 * 36 * 4);
    float* Whd2_0  = (float*)take(64 * 20 * 4);
    float* Whd2_1  = (float*)take(64 * 20 * 4);
    float* Wht2_0  = (float*)take(64 * 20 * 4);
    float* Wht2_1  = (float*)take(64 * 20 * 4);
    uint* hs_dev    = (uint*)take((size_t)NDEV * 32 * 4);
    float* als_dev  = (float*)take((size_t)NDEV * 4 * 4);
    float* aldx_dev = (float*)take((size_t)NDEV * 4 * 4);
    uint* hs_task   = (uint*)take((size_t)NTASK * 32 * 4);
    float* als_task = (float*)take((size_t)NTASK * 4 * 4);
    float* aldx_task= (float*)take((size_t)NTASK * 4 * 4);
    uint* x_task1   = (uint*)take((size_t)NTASK * 32 * 4);  // packed bf16, 64 ch
    uint* x_dev1    = (uint*)take((size_t)NDEV * 32 * 4);   // packed bf16, 64 ch
    // pairs (4MB each) alias x_task1 (12.8MB): written by bucketB, consumed by
    // bucketC, both strictly before gat_agg_l1 writes x_task1 (in-order stream).
    uint* pairs_w = (uint*)x_task1;
    uint* pairs_b = pairs_w + NE;
    (void)ws_size; (void)n_in; (void)in_sizes; (void)out_size;

    prep_weights<<<1, 64, 0, stream>>>(
        W1a_src, a1a_src, W1a_dst, a1a_dst, W1b_src, a1b_src, W1b_dst, a1b_dst,
        W2a_src, a2a_src, W2a_dst, a2a_dst, W2b_src, a2b_src, W2b_dst, a2b_dst,
        Whd1_0, Whd1_1, Wht1_0, Wht1_1, Whd2_0, Whd2_1, Wht2_0, Wht2_1);

    // CSR build: 2-level bucket sort (both directions in each launch)
    bucketA<<<2 * NBLK_AB, 256, 0, stream>>>(writes_dst, wb_dst, bh_t, bh_d);
    scanB1<<<2 * NBK, 256, 0, stream>>>(bh_t, bh_d, rowtot);
    scanB2<<<1, 256, 0, stream>>>(rowtot, coarse_t, coarse_d, offs_task, offs_dev);
    bucketB<<<2 * NBLK_AB, 256, 0, stream>>>(writes_src, writes_dst, wb_src, wb_dst,
                                             bh_t, bh_d, coarse_t, coarse_d, pairs_w, pairs_b);
    bucketC<<<2 * NBK, 256, 0, stream>>>(pairs_w, coarse_t, offs_task, s_w,
                                         pairs_b, coarse_d, offs_dev, s_b);

    // layer 1 transforms: 2 halves x 2 node types in one launch
    int nbHalf = (NDEV + 255) / 256 + (NTASK + 255) / 256;
    gemm_quad<36, 32, 4, 4, 32><<<2 * nbHalf, 256, 0, stream>>>(
        x_dev, NDEV, Whd1_0, Whd1_1, hs_dev, als_dev, aldx_dev,
        x_task, NTASK, Wht1_0, Wht1_1, hs_task, als_task, aldx_task);

    // layer 1 aggregation (both directions, one launch) -> packed bf16 x1
    int nbagg = (NTASK + 3) / 4 + (NDEV + 3) / 4;
    gat_agg_l1<<<nbagg, 256, 0, stream>>>(
        offs_task, s_w, als_dev, aldx_task, hs_dev, b1a, x_task1,
        offs_dev, s_b, als_task, aldx_dev, hs_task, b1b, x_dev1);

    // layer 2 transforms (packed-bf16 input)
    gemm_quad_b16<20, 16, 1, 1, 16><<<2 * nbHalf, 256, 0, stream>>>(
        x_dev1, NDEV, Whd2_0, Whd2_1, hs_dev, als_dev, aldx_dev,
        x_task1, NTASK, Wht2_0, Wht2_1, hs_task, als_task, aldx_task);

    // layer 2 aggregation -> final outputs
    gat_agg_l2<<<nbagg, 256, 0, stream>>>(
        offs_task, s_w, als_dev, aldx_task, hs_dev, b2a, out_task2,
        offs_dev, s_b, als_task, aldx_dev, hs_task, b2b, out_dev2);
}